// Round 7
// baseline (38.087 us; speedup 1.0000x reference)
//
#include <hip/hip_runtime.h>
#include <math.h>

#define RPOOL 5
#define RPW   8   // rows per wave

__global__ __launch_bounds__(256, 4)
void minmax_pool_sort_kernel(const float* __restrict__ x,
                             const int* __restrict__ lengths,
                             float* __restrict__ out,
                             int n, int L) {
    const int lane = threadIdx.x & 63;
    const int wid  = threadIdx.x >> 6;
    const int base = (blockIdx.x * 4 + wid) * RPW;   // first row owned by this wave
    if (base >= n) return;

    // ONE vector load fetches all 8 lengths for this wave; broadcast to SGPRs.
    int myLen = RPOOL;
    if (lane < RPW && base + lane < n) myLen = lengths[base + lane];
    int lens[RPW];
#pragma unroll
    for (int k = 0; k < RPW; ++k)
        lens[k] = __builtin_amdgcn_readlane(myLen, k);   // wave-uniform SGPR

    // Ping-pong in-flight state (indices compile-time under full unroll).
    float4 vbuf[2][RPOOL];
    int    tbuf[2][RPOOL];
    int    sbuf[2][RPOOL];
    int    ebuf[2][RPOOL];

    // Issue the 5 window loads for row (base+k) into slot p.
    auto issue = [&](int k, int p) {
        const int l = lens[k];
        const float* xr = x + (long long)(base + k) * L;
#pragma unroll
        for (int j = 0; j < RPOOL; ++j) {
            const int s  = (j * l) / RPOOL;                    // floor(j*l/R)
            const int e  = ((j + 1) * l + RPOOL - 1) / RPOOL;  // ceil((j+1)*l/R)
            const int sa = s & ~3;                             // 16B-aligned start
            const int t  = sa + lane * 4;
            sbuf[p][j] = s; ebuf[p][j] = e; tbuf[p][j] = t;
            const int idx = (t < e) ? t : 0;                   // clamp OOB lanes into row
            vbuf[p][j] = *reinterpret_cast<const float4*>(xr + idx);
        }
    };

    // Consume slot p -> sorted 10 values -> store row (base+k).
    auto compute = [&](int k, int p) {
        float mx[RPOOL], mn[RPOOL];
#pragma unroll
        for (int j = 0; j < RPOOL; ++j) {
            const float vv0 = vbuf[p][j].x, vv1 = vbuf[p][j].y;
            const float vv2 = vbuf[p][j].z, vv3 = vbuf[p][j].w;
            const int t = tbuf[p][j];
            const int s = sbuf[p][j], e = ebuf[p][j];
            const bool ok0 = (t     >= s) & (t     < e);
            const bool ok1 = (t + 1 >= s) & (t + 1 < e);
            const bool ok2 = (t + 2 >= s) & (t + 2 < e);
            const bool ok3 = (t + 3 >= s) & (t + 3 < e);
            const float m0 = ok0 ? vv0 : -INFINITY, n0 = ok0 ? vv0 : INFINITY;
            const float m1 = ok1 ? vv1 : -INFINITY, n1 = ok1 ? vv1 : INFINITY;
            const float m2 = ok2 ? vv2 : -INFINITY, n2 = ok2 ? vv2 : INFINITY;
            const float m3 = ok3 ? vv3 : -INFINITY, n3 = ok3 ? vv3 : INFINITY;
            mx[j] = fmaxf(fmaxf(m0, m1), fmaxf(m2, m3));
            mn[j] = fminf(fminf(n0, n1), fminf(n2, n3));
        }

        // Step-major butterfly: 10 independent shuffles per level.
#pragma unroll
        for (int off = 32; off > 0; off >>= 1) {
#pragma unroll
            for (int j = 0; j < RPOOL; ++j) {
                mx[j] = fmaxf(mx[j], __shfl_xor(mx[j], off, 64));
                mn[j] = fminf(mn[j], __shfl_xor(mn[j], off, 64));
            }
        }

        float vals[2 * RPOOL];
#pragma unroll
        for (int j = 0; j < RPOOL; ++j) { vals[j] = mx[j]; vals[RPOOL + j] = mn[j]; }

        // Sort 10 ascending — fully-unrolled bubble network (known correct).
#pragma unroll
        for (int i = 0; i < 2 * RPOOL - 1; ++i) {
#pragma unroll
            for (int q = 0; q < 2 * RPOOL - 1 - i; ++q) {
                const float a = vals[q];
                const float b = vals[q + 1];
                vals[q]     = fminf(a, b);
                vals[q + 1] = fmaxf(a, b);
            }
        }

        float ov = vals[0];
#pragma unroll
        for (int q = 1; q < 2 * RPOOL; ++q) ov = (lane == q) ? vals[q] : ov;
        if (lane < 2 * RPOOL) out[(long long)(base + k) * (2 * RPOOL) + lane] = ov;
    };

    // Software pipeline: loads for row k+1 fly under row k's compute.
    issue(0, 0);
#pragma unroll
    for (int k = 0; k < RPW; ++k) {
        if (k + 1 < RPW && base + k + 1 < n) issue(k + 1, (k + 1) & 1);
        if (base + k < n) compute(k, k & 1);
    }
}

extern "C" void kernel_launch(void* const* d_in, const int* in_sizes, int n_in,
                              void* d_out, int out_size, void* d_ws, size_t ws_size,
                              hipStream_t stream) {
    const float* x       = (const float*)d_in[0];
    const int*   lengths = (const int*)d_in[1];
    float*       out     = (float*)d_out;

    const int n = in_sizes[1];            // N rows
    const int L = in_sizes[0] / n;        // row stride (1000)

    const int rows_per_block = 4 * RPW;   // 4 waves x 8 rows
    const int blocks = (n + rows_per_block - 1) / rows_per_block;
    hipLaunchKernelGGL(minmax_pool_sort_kernel, dim3(blocks), dim3(256), 0, stream,
                       x, lengths, out, n, L);
}